// Round 1
// baseline (173.428 us; speedup 1.0000x reference)
//
#include <hip/hip_runtime.h>
#include <hip/hip_bf16.h>
#include <math.h>

#define N_TOK 4096
#define DIM   1024

typedef __attribute__((ext_vector_type(8))) short s16x8;
typedef __attribute__((ext_vector_type(4))) float f32x4;

__device__ inline short to_bf16(float f) {
  union { float f; unsigned u; } v; v.f = f;
  unsigned r = v.u + 0x7FFFu + ((v.u >> 16) & 1u);   // RNE
  return (short)(r >> 16);
}

// ---------------- cast fp32 -> bf16 ----------------
__global__ void cast_bf16_kernel(const float* __restrict__ in, short* __restrict__ out, int n) {
  int i = (blockIdx.x * blockDim.x + threadIdx.x) * 4;
  if (i >= n) return;
  float4 v = *reinterpret_cast<const float4*>(in + i);
  short4 o;
  o.x = to_bf16(v.x); o.y = to_bf16(v.y); o.z = to_bf16(v.z); o.w = to_bf16(v.w);
  *reinterpret_cast<short4*>(out + i) = o;
}

// ---------------- transpose + cast: in[R][C] fp32 -> out[C][R] bf16 ----------------
__global__ void transpose_cast_kernel(const float* __restrict__ in, short* __restrict__ out,
                                      int R, int C) {
  __shared__ float tile[32][33];
  int bx = blockIdx.x * 32, by = blockIdx.y * 32;
  int tx = threadIdx.x, ty = threadIdx.y;   // block (32,8)
  #pragma unroll
  for (int i = 0; i < 32; i += 8)
    tile[ty + i][tx] = in[(size_t)(by + ty + i) * C + (bx + tx)];
  __syncthreads();
  #pragma unroll
  for (int i = 0; i < 32; i += 8)
    out[(size_t)(bx + ty + i) * R + (by + tx)] = to_bf16(tile[tx][ty + i]);
}

// fast tanh via exp2-based __expf: 1 - 2/(e^{2x}+1). Correct limits at +/-inf.
__device__ inline float fast_tanh(float x) {
  float e = __expf(2.0f * x);
  return 1.0f - 2.0f / (e + 1.0f);
}

// ---------------- NT GEMM: C[M][N] = A[M,K] * B[N,K]^T + epilogue ----------------
// EPI 0: + bias[col], store bf16
// EPI 1: + bias[row], store bf16
// EPI 2: p = exp(tanh(acc)*scale), store bf16, atomic rowsum
// EPI 3: acc / l[row], store fp32
template<int EPI>
__global__ __launch_bounds__(256, 2)
void gemm_nt(const short* __restrict__ A, const short* __restrict__ B,
             const float* __restrict__ aux, short* __restrict__ Cb,
             float* __restrict__ Cf, float* __restrict__ rowsum,
             int M, int N, int K, float scale)
{
  __shared__ short As[128 * 64];
  __shared__ short Bs[128 * 64];
  const int t    = threadIdx.x;
  const int lane = t & 63;
  const int wid  = t >> 6;          // 4 waves
  const int wr   = wid >> 1, wc = wid & 1;
  const int l15  = lane & 15, l4 = lane >> 4;

  const short* Abase = A + (size_t)blockIdx.y * 128 * K;
  const short* Bbase = B + (size_t)blockIdx.x * 128 * K;

  f32x4 acc[4][4];
  #pragma unroll
  for (int m = 0; m < 4; ++m)
    #pragma unroll
    for (int n = 0; n < 4; ++n)
      acc[m][n] = f32x4{0.f, 0.f, 0.f, 0.f};

  // staging map: s = t + i*256 -> row = s>>3 (0..127), slot = s&7 (8 slots of 16B per 64-elem row)
  int rowi[4], sli[4];
  #pragma unroll
  for (int i = 0; i < 4; ++i) { int s = t + i * 256; rowi[i] = s >> 3; sli[i] = s & 7; }

  s16x8 ra[4], rb[4];
  const int nk = K >> 6;
  #pragma unroll
  for (int i = 0; i < 4; ++i) {
    ra[i] = *(const s16x8*)(Abase + (size_t)rowi[i] * K + sli[i] * 8);
    rb[i] = *(const s16x8*)(Bbase + (size_t)rowi[i] * K + sli[i] * 8);
  }

  for (int kt = 0; kt < nk; ++kt) {
    __syncthreads();
    #pragma unroll
    for (int i = 0; i < 4; ++i) {
      int ps = sli[i] ^ (rowi[i] & 7);             // XOR swizzle: bank-spread, keeps 16B align
      *(s16x8*)(&As[rowi[i] * 64 + ps * 8]) = ra[i];
      *(s16x8*)(&Bs[rowi[i] * 64 + ps * 8]) = rb[i];
    }
    __syncthreads();
    if (kt + 1 < nk) {
      const int ko = (kt + 1) * 64;
      #pragma unroll
      for (int i = 0; i < 4; ++i) {
        ra[i] = *(const s16x8*)(Abase + (size_t)rowi[i] * K + ko + sli[i] * 8);
        rb[i] = *(const s16x8*)(Bbase + (size_t)rowi[i] * K + ko + sli[i] * 8);
      }
    }
    #pragma unroll
    for (int kk = 0; kk < 2; ++kk) {
      s16x8 af[4], bfv[4];
      #pragma unroll
      for (int m = 0; m < 4; ++m) {
        int row = wr * 64 + m * 16 + l15;
        int ps  = (kk * 4 + l4) ^ (row & 7);
        af[m] = *(const s16x8*)(&As[row * 64 + ps * 8]);
      }
      #pragma unroll
      for (int n = 0; n < 4; ++n) {
        int row = wc * 64 + n * 16 + l15;
        int ps  = (kk * 4 + l4) ^ (row & 7);
        bfv[n] = *(const s16x8*)(&Bs[row * 64 + ps * 8]);
      }
      #pragma unroll
      for (int m = 0; m < 4; ++m)
        #pragma unroll
        for (int n = 0; n < 4; ++n)
          acc[m][n] = __builtin_amdgcn_mfma_f32_16x16x32_bf16(af[m], bfv[n], acc[m][n], 0, 0, 0);
    }
  }

  const int rbase = blockIdx.y * 128 + wr * 64;
  const int cbase = blockIdx.x * 128 + wc * 64;

  #pragma unroll
  for (int m = 0; m < 4; ++m) {
    #pragma unroll
    for (int r = 0; r < 4; ++r) {
      const int grow = rbase + m * 16 + l4 * 4 + r;
      if (EPI == 2) {
        float rs = 0.f;
        #pragma unroll
        for (int n = 0; n < 4; ++n) {
          float p = __expf(fast_tanh(acc[m][n][r]) * scale);
          rs += p;
          Cb[(size_t)grow * N + (cbase + n * 16 + l15)] = to_bf16(p);
        }
        rs += __shfl_xor(rs, 1);
        rs += __shfl_xor(rs, 2);
        rs += __shfl_xor(rs, 4);
        rs += __shfl_xor(rs, 8);
        if (l15 == 0) atomicAdd(&rowsum[grow], rs);
      } else if (EPI == 3) {
        const float invl = 1.f / aux[grow];
        #pragma unroll
        for (int n = 0; n < 4; ++n)
          Cf[(size_t)grow * N + (cbase + n * 16 + l15)] = acc[m][n][r] * invl;
      } else {
        #pragma unroll
        for (int n = 0; n < 4; ++n) {
          const int gcol = cbase + n * 16 + l15;
          const float bias = (EPI == 0) ? aux[gcol] : aux[grow];
          Cb[(size_t)grow * N + gcol] = to_bf16(acc[m][n][r] + bias);
        }
      }
    }
  }
}

extern "C" void kernel_launch(void* const* d_in, const int* in_sizes, int n_in,
                              void* d_out, int out_size, void* d_ws, size_t ws_size,
                              hipStream_t stream) {
  const float* x  = (const float*)d_in[0];
  const float* Wq = (const float*)d_in[1];
  const float* bq = (const float*)d_in[2];
  const float* Wk = (const float*)d_in[3];
  const float* bk = (const float*)d_in[4];
  const float* Wv = (const float*)d_in[5];
  const float* bv = (const float*)d_in[6];
  float* out = (float*)d_out;

  char* ws = (char*)d_ws;
  short* xb   = (short*)(ws);                      //  8 MB  x bf16 [4096][1024]
  short* qb   = (short*)(ws + (8ull  << 20));      //  8 MB
  short* kb   = (short*)(ws + (16ull << 20));      //  8 MB
  short* vTb  = (short*)(ws + (24ull << 20));      //  8 MB  v^T [1024][4096]
  short* WqT  = (short*)(ws + (32ull << 20));      //  2 MB
  short* WkT  = (short*)(ws + (34ull << 20));      //  2 MB
  short* WvT  = (short*)(ws + (36ull << 20));      //  2 MB
  float* lsum = (float*)(ws + (38ull << 20));      // 16 KB
  short* P    = (short*)(ws + (40ull << 20));      // 32 MB  P bf16 [4096][4096]

  hipMemsetAsync(lsum, 0, N_TOK * sizeof(float), stream);

  cast_bf16_kernel<<<(N_TOK * DIM / 4 + 255) / 256, 256, 0, stream>>>(x, xb, N_TOK * DIM);
  dim3 tgrid(DIM / 32, DIM / 32), tblk(32, 8);
  transpose_cast_kernel<<<tgrid, tblk, 0, stream>>>(Wq, WqT, DIM, DIM);
  transpose_cast_kernel<<<tgrid, tblk, 0, stream>>>(Wk, WkT, DIM, DIM);
  transpose_cast_kernel<<<tgrid, tblk, 0, stream>>>(Wv, WvT, DIM, DIM);

  dim3 blk(256);
  // q = x@Wq + bq ; k = x@Wk + bk   (M=4096, N=1024, K=1024)
  gemm_nt<0><<<dim3(DIM / 128, N_TOK / 128), blk, 0, stream>>>(
      xb, WqT, bq, qb, nullptr, nullptr, N_TOK, DIM, DIM, 0.f);
  gemm_nt<0><<<dim3(DIM / 128, N_TOK / 128), blk, 0, stream>>>(
      xb, WkT, bk, kb, nullptr, nullptr, N_TOK, DIM, DIM, 0.f);
  // vT[j][i] = sum_kk WvT[j][kk]*x[i][kk] + bv[j]   (M=1024, N=4096, K=1024)
  gemm_nt<1><<<dim3(N_TOK / 128, DIM / 128), blk, 0, stream>>>(
      WvT, xb, bv, vTb, nullptr, nullptr, DIM, N_TOK, DIM, 0.f);
  // P = exp(tanh(q k^T) * 1/32), rowsum -> lsum   (M=N=4096, K=1024)
  gemm_nt<2><<<dim3(N_TOK / 128, N_TOK / 128), blk, 0, stream>>>(
      qb, kb, nullptr, P, nullptr, lsum, N_TOK, N_TOK, DIM, 0.03125f);
  // out = (P @ v) / lsum[row]   (M=4096, N=1024, K=4096)
  gemm_nt<3><<<dim3(DIM / 128, N_TOK / 128), blk, 0, stream>>>(
      P, vTb, lsum, nullptr, out, nullptr, N_TOK, DIM, N_TOK, 0.f);
}